// Round 7
// baseline (87.474 us; speedup 1.0000x reference)
//
#include <hip/hip_runtime.h>
#include <hip/hip_bf16.h>

#define T_DIM 4096
#define C_DIM 1024
#define H_DIM 64
#define B_DIM 4

typedef __attribute__((ext_vector_type(8))) short short8v;
typedef __attribute__((ext_vector_type(4))) short short4v;
typedef __attribute__((ext_vector_type(4))) float float4v;
typedef __attribute__((ext_vector_type(16))) float float16v;

__device__ __forceinline__ unsigned short f2bf(float f) {
    __hip_bfloat16 h = __float2bfloat16(f);
    return *reinterpret_cast<unsigned short*>(&h);
}

// permuted position within a 32-row block for V storage (PV frag = one 16B load)
__device__ __forceinline__ int vperm(int t5) {
    return ((t5 & 12) << 1) | (t5 & 3) | ((t5 & 16) >> 2);
}

#define GLL16(gsrc, ldst)                                                         \
    __builtin_amdgcn_global_load_lds(                                             \
        (const __attribute__((address_space(1))) unsigned int*)(gsrc),            \
        (__attribute__((address_space(3))) unsigned int*)(ldst), 16, 0, 0)

// ---------------------------------------------------------------------------
// W prep via LDS transpose: coalesced f32 reads AND coalesced bf16 writes.
// grid 48 = (3 m) x (16 k-chunks). wt[(m*64+col)*1024 + k] = bf16(W[k][col]).
// FIX (r6 bug): each thread now loads 4 rows -> full 64-row tile coverage
// (was 16 rows -> uninitialized LDS -> NaN downstream).
// ---------------------------------------------------------------------------
__global__ __launch_bounds__(256) void wprep(
    const float* __restrict__ Wq, const float* __restrict__ Wk,
    const float* __restrict__ Wv, unsigned short* __restrict__ wt)
{
    __shared__ float tile[64][65];
    const int t  = threadIdx.x;
    const int m  = blockIdx.x >> 4;
    const int k0 = (blockIdx.x & 15) * 64;
    const float* __restrict__ W = (m == 0) ? Wq : (m == 1) ? Wk : Wv;

    const int kr = t >> 4, c4 = (t & 15) * 4;
#pragma unroll
    for (int j = 0; j < 4; ++j) {
        const int row = kr + j * 16;
        const float4 v = *(const float4*)(W + (size_t)(k0 + row) * 64 + c4);
        tile[row][c4 + 0] = v.x; tile[row][c4 + 1] = v.y;
        tile[row][c4 + 2] = v.z; tile[row][c4 + 3] = v.w;
    }
    __syncthreads();

    const int col = t >> 2, q = t & 3;
    short8v s0, s1;
#pragma unroll
    for (int j = 0; j < 8; ++j) s0[j] = (short)f2bf(tile[q * 16 + j][col]);
#pragma unroll
    for (int j = 0; j < 8; ++j) s1[j] = (short)f2bf(tile[q * 16 + 8 + j][col]);
    unsigned short* dst = wt + (size_t)(m * 64 + col) * 1024 + k0 + q * 16;
    *(short8v*)dst = s0;
    *(short8v*)(dst + 8) = s1;
}

// ---------------------------------------------------------------------------
// QKV projection: LDS GEMM with 32x32x16 MFMA. Block = 64 rows x 192 cols,
// BK=64, 16 K-steps, 512 thr = 8 waves = 2 rg x 2 cgr x 2 K-half (K-split,
// combined at end through LDS). x reg-staged as bf16 (T14: loads issued
// before compute, cvt+ds_write after); wt staged via global_load_lds with
// pre-inverse-swizzled source. All LDS tiles granule-XOR swizzled (^row&7).
// ---------------------------------------------------------------------------
__global__ __launch_bounds__(512, 2) void qkv_gemm(
    const float* __restrict__ x, const unsigned short* __restrict__ wt,
    const float* __restrict__ bq, const float* __restrict__ bk,
    const float* __restrict__ bv,
    unsigned short* __restrict__ qb, unsigned short* __restrict__ kmat,
    unsigned short* __restrict__ vP)
{
    __shared__ __align__(16) unsigned char lx[2][8192];    // 64 rows x 128B bf16
    __shared__ __align__(16) unsigned char lw[2][24576];   // 192 cols x 128B bf16

    const int t    = threadIdx.x;
    const int lane = t & 63;
    const int w    = t >> 6;
    const int l31  = lane & 31;
    const int hi   = lane >> 5;
    const int r0   = blockIdx.x * 64;

    const int rg  = w & 1;
    const int cgr = (w >> 1) & 1;
    const int kh  = w >> 2;

    // staging constants
    const int srow  = t >> 3;                    // 0..63
    const int soct  = t & 7;                     // 0..7
    const int sphys = soct ^ (srow & 7);
    const float* __restrict__ xsrc = x + (size_t)(r0 + srow) * C_DIM + soct * 8;
    const int wgs = (t & 7) ^ ((t >> 3) & 7);    // inverse-swizzled wt granule
    const unsigned char* __restrict__ wB = (const unsigned char*)wt;

    float16v acc[3];
#pragma unroll
    for (int cg = 0; cg < 3; ++cg)
#pragma unroll
        for (int e = 0; e < 16; ++e) acc[cg][e] = 0.f;

#define WSTAGE(p, kb)                                                             \
    {                                                                             \
        _Pragma("unroll")                                                         \
        for (int i = 0; i < 3; ++i)                                               \
            GLL16(wB + (size_t)(i * 64 + (t >> 3)) * 2048 + (kb) * 128 + wgs * 16,\
                  &lw[p][(i * 512 + t) * 16]);                                    \
    }

    // prologue: stage step 0
    {
        const float4 a0 = *(const float4*)(xsrc);
        const float4 a1 = *(const float4*)(xsrc + 4);
        WSTAGE(0, 0);
        short8v xs;
        xs[0] = (short)f2bf(a0.x); xs[1] = (short)f2bf(a0.y);
        xs[2] = (short)f2bf(a0.z); xs[3] = (short)f2bf(a0.w);
        xs[4] = (short)f2bf(a1.x); xs[5] = (short)f2bf(a1.y);
        xs[6] = (short)f2bf(a1.z); xs[7] = (short)f2bf(a1.w);
        *(short8v*)&lx[0][srow * 128 + sphys * 16] = xs;
    }
    __syncthreads();

    const int arow = rg * 32 + l31;
    const int axor = arow & 7;

    for (int kb = 0; kb < 16; ++kb) {
        const int p = kb & 1;
        float4 na = {0,0,0,0}, nb = {0,0,0,0};
        if (kb < 15) {
            na = *(const float4*)(xsrc + (kb + 1) * 64);
            nb = *(const float4*)(xsrc + (kb + 1) * 64 + 4);
            WSTAGE(p ^ 1, kb + 1);
        }

        short8v af[2];
#pragma unroll
        for (int ks = 0; ks < 2; ++ks) {
            const int kg = kh * 4 + ks * 2 + hi;
            af[ks] = *(const short8v*)&lx[p][arow * 128 + (kg ^ axor) * 16];
        }
#pragma unroll
        for (int cg = 0; cg < 3; ++cg) {
            const int col = cgr * 96 + cg * 32 + l31;
#pragma unroll
            for (int ks = 0; ks < 2; ++ks) {
                const int kg = kh * 4 + ks * 2 + hi;
                const short8v bf =
                    *(const short8v*)&lw[p][col * 128 + ((kg ^ (col & 7))) * 16];
                acc[cg] = __builtin_amdgcn_mfma_f32_32x32x16_bf16(af[ks], bf, acc[cg], 0, 0, 0);
            }
        }

        if (kb < 15) {
            short8v xs;
            xs[0] = (short)f2bf(na.x); xs[1] = (short)f2bf(na.y);
            xs[2] = (short)f2bf(na.z); xs[3] = (short)f2bf(na.w);
            xs[4] = (short)f2bf(nb.x); xs[5] = (short)f2bf(nb.y);
            xs[6] = (short)f2bf(nb.z); xs[7] = (short)f2bf(nb.w);
            *(short8v*)&lx[p ^ 1][srow * 128 + sphys * 16] = xs;
        }
        __syncthreads();
    }

    // K-half combine: kh=1 waves write partials to LDS (reuse lw = 48KB)
    float* comm = (float*)lw;
    if (kh == 1) {
        const int base = ((w - 4) * 64 + lane) * 48;
#pragma unroll
        for (int cg = 0; cg < 3; ++cg)
#pragma unroll
            for (int e = 0; e < 16; ++e) comm[base + cg * 16 + e] = acc[cg][e];
    }
    __syncthreads();
    if (kh == 0) {
        const int base = (w * 64 + lane) * 48;
#pragma unroll
        for (int cg = 0; cg < 3; ++cg)
#pragma unroll
            for (int e = 0; e < 16; ++e) acc[cg][e] += comm[base + cg * 16 + e];

        const float qs = 0.03125f * 1.44269504088896f;  // C^-0.5 * log2(e)
#pragma unroll
        for (int cg = 0; cg < 3; ++cg) {
            const int cabs = cgr * 96 + cg * 32 + l31;
            const int m    = cabs >> 6;
            const int h    = cabs & 63;
            const float bb = ((m == 0) ? bq : (m == 1) ? bk : bv)[h];
#pragma unroll
            for (int reg = 0; reg < 16; ++reg) {
                const int row = r0 + rg * 32 + (reg & 3) + 8 * (reg >> 2) + 4 * hi;
                const float vv = acc[cg][reg] + bb;
                if (m == 0) {
                    qb[(size_t)row * 64 + h] = f2bf(vv * qs);
                } else if (m == 1) {
                    kmat[(size_t)row * 64 + h] = f2bf(vv);
                } else {
                    const int b_i = row >> 12;
                    const int tt  = row & 4095;
                    const int tp  = (tt & ~31) | vperm(tt & 31);
                    vP[((size_t)b_i * 64 + h) * T_DIM + tp] = f2bf(vv);
                }
            }
        }
    }
#undef WSTAGE
}

// ---------------------------------------------------------------------------
// Causal attention via MFMA, no max-subtraction (|s*log2e| < ~2, exp2 safe).
// grid 512 x 512 thr (8 waves). Block = 32 q-rows x batch; 8 waves split kv
// 8 ways; wave does TWO 16-row q tiles. 2-stage K prefetch (static even/odd
// regs), V issued at step top, f32 lsum, unmasked fast path, setprio on MFMA.
// Complementary block pairing balances per-CU work. 8-way LDS combine.
// ---------------------------------------------------------------------------
__global__ __launch_bounds__(512, 4) void attn_mfma(
    const unsigned short* __restrict__ qb, const unsigned short* __restrict__ kmat,
    const unsigned short* __restrict__ vP, float* __restrict__ out)
{
    __shared__ float partO[8][32][68];
    __shared__ float partl[8][32];

    const int w    = threadIdx.x >> 6;
    const int lane = threadIdx.x & 63;
    const int l15  = lane & 15;
    const int g    = lane >> 4;
    const int i    = blockIdx.x;
    const int p2   = (i & 255) >> 2;
    const int b    = i & 3;
    const int tt   = (i < 256) ? (127 - p2) : p2;
    const int q0   = tt * 32;
    const int n    = tt + 1;

    const unsigned short* __restrict__ qbase = qb + ((size_t)b * T_DIM + q0) * 64;
    short8v qf[2][2];
    qf[0][0] = *(const short8v*)(qbase + (size_t)l15 * 64 + 8 * g);
    qf[0][1] = *(const short8v*)(qbase + (size_t)l15 * 64 + 32 + 8 * g);
    qf[1][0] = *(const short8v*)(qbase + (size_t)(16 + l15) * 64 + 8 * g);
    qf[1][1] = *(const short8v*)(qbase + (size_t)(16 + l15) * 64 + 32 + 8 * g);

    const unsigned short* __restrict__ kbase = kmat + (size_t)b * T_DIM * 64;
    const unsigned short* __restrict__ vbase = vP + (size_t)b * 64 * T_DIM;

    float4v acc[2][4];
#pragma unroll
    for (int qt = 0; qt < 2; ++qt)
#pragma unroll
        for (int f = 0; f < 4; ++f) acc[qt][f] = (float4v){0.f, 0.f, 0.f, 0.f};
    float lsum[2] = {0.f, 0.f};

    const int rem = n & 7;
    const int cnt = (n >> 3) + (w < rem ? 1 : 0);
    const int st  = w * (n >> 3) + (w < rem ? w : rem);

#define LOADK(KA, KV0)                                                        \
    {                                                                         \
        const unsigned short* kr_ = kbase + (size_t)((KV0) + l15) * 64 + 8*g; \
        KA[0] = *(const short8v*)kr_;                                         \
        KA[1] = *(const short8v*)(kr_ + 32);                                  \
        KA[2] = *(const short8v*)(kr_ + 1024);                                \
        KA[3] = *(const short8v*)(kr_ + 1056);                                \
    }
#define LOADV(KV0)                                                            \
    {                                                                         \
        _Pragma("unroll")                                                     \
        for (int f_ = 0; f_ < 4; ++f_)                                        \
            vb[f_] = *(const short8v*)(vbase +                                \
                (size_t)(f_ * 16 + l15) * T_DIM + (KV0) + 8 * g);             \
    }
#define STEP(KA, KV0)                                                         \
    {                                                                         \
        _Pragma("unroll")                                                     \
        for (int qt = 0; qt < 2; ++qt) {                                      \
            const float4v z_ = (float4v){0.f, 0.f, 0.f, 0.f};                 \
            __builtin_amdgcn_s_setprio(1);                                    \
            float4v slo = __builtin_amdgcn_mfma_f32_16x16x32_bf16(KA[0], qf[qt][0], z_, 0, 0, 0); \
            slo = __builtin_amdgcn_mfma_f32_16x16x32_bf16(KA[1], qf[qt][1], slo, 0, 0, 0); \
            float4v shi = __builtin_amdgcn_mfma_f32_16x16x32_bf16(KA[2], qf[qt][0], z_, 0, 0, 0); \
            shi = __builtin_amdgcn_mfma_f32_16x16x32_bf16(KA[3], qf[qt][1], shi, 0, 0, 0); \
            __builtin_amdgcn_s_setprio(0);                                    \
            short8v pa;                                                       \
            float ls = 0.f;                                                   \
            if ((KV0) + 31 <= q0 + 16 * qt) {                                 \
                _Pragma("unroll")                                             \
                for (int r = 0; r < 4; ++r) {                                 \
                    const float plo = exp2f(slo[r]);                          \
                    const float phi = exp2f(shi[r]);                          \
                    pa[r]     = (short)f2bf(plo);                             \
                    pa[4 + r] = (short)f2bf(phi);                             \
                    ls += plo + phi;                                          \
                }                                                             \
            } else {                                                          \
                const int qabs = q0 + 16 * qt + l15;                          \
                _Pragma("unroll")                                             \
                for (int r = 0; r < 4; ++r) {                                 \
                    const int kvlo = (KV0) + 4 * g + r;                       \
                    const float plo = (kvlo <= qabs) ? exp2f(slo[r]) : 0.f;   \
                    const float phi = (kvlo + 16 <= qabs) ? exp2f(shi[r]) : 0.f; \
                    pa[r]     = (short)f2bf(plo);                             \
                    pa[4 + r] = (short)f2bf(phi);                             \
                    ls += plo + phi;                                          \
                }                                                             \
            }                                                                 \
            lsum[qt] += ls;                                                   \
            __builtin_amdgcn_s_setprio(1);                                    \
            _Pragma("unroll")                                                 \
            for (int f = 0; f < 4; ++f)                                       \
                acc[qt][f] = __builtin_amdgcn_mfma_f32_16x16x32_bf16(pa, vb[f], acc[qt][f], 0, 0, 0); \
            __builtin_amdgcn_s_setprio(0);                                    \
        }                                                                     \
    }

    short8v kaA[4], kaB[4], vb[4];
    if (cnt > 0) {
        LOADK(kaA, st * 32);
        int s = 0;
        while (true) {
            const int kv0 = (st + s) * 32;
            LOADV(kv0);
            if (s + 1 < cnt) LOADK(kaB, (st + s + 1) * 32);
            STEP(kaA, kv0);
            if (++s >= cnt) break;
            const int kv1 = (st + s) * 32;
            LOADV(kv1);
            if (s + 1 < cnt) LOADK(kaA, (st + s + 1) * 32);
            STEP(kaB, kv1);
            if (++s >= cnt) break;
        }
    }
#undef LOADK
#undef LOADV
#undef STEP

#pragma unroll
    for (int qt = 0; qt < 2; ++qt) {
        lsum[qt] += __shfl_xor(lsum[qt], 16);
        lsum[qt] += __shfl_xor(lsum[qt], 32);
    }

#pragma unroll
    for (int qt = 0; qt < 2; ++qt)
#pragma unroll
        for (int f = 0; f < 4; ++f)
#pragma unroll
            for (int r = 0; r < 4; ++r)
                partO[w][16 * qt + 4 * g + r][16 * f + l15] = acc[qt][f][r];
    if (g == 0) {
        partl[w][l15]      = lsum[0];
        partl[w][16 + l15] = lsum[1];
    }
    __syncthreads();

    const int row = threadIdx.x >> 4;
    const int c0  = (threadIdx.x & 15) * 4;
    float lt = 0.f;
#pragma unroll
    for (int ww = 0; ww < 8; ++ww) lt += partl[ww][row];
    const float inv = 1.f / lt;
    float4 o = make_float4(0.f, 0.f, 0.f, 0.f);
#pragma unroll
    for (int ww = 0; ww < 8; ++ww) {
        const float4 s = *(const float4*)&partO[ww][row][c0];
        o.x += s.x; o.y += s.y; o.z += s.z; o.w += s.w;
    }
    o.x *= inv; o.y *= inv; o.z *= inv; o.w *= inv;
    *(float4*)(out + ((size_t)b * T_DIM + q0 + row) * 64 + c0) = o;
}

extern "C" void kernel_launch(void* const* d_in, const int* in_sizes, int n_in,
                              void* d_out, int out_size, void* d_ws, size_t ws_size,
                              hipStream_t stream) {
    const float* x  = (const float*)d_in[0];
    const float* Wq = (const float*)d_in[1];
    const float* bq = (const float*)d_in[2];
    const float* Wk = (const float*)d_in[3];
    const float* bk = (const float*)d_in[4];
    const float* Wv = (const float*)d_in[5];
    const float* bv = (const float*)d_in[6];
    float* out = (float*)d_out;

    const size_t rows = (size_t)B_DIM * T_DIM;            // 16384
    char* ws = (char*)d_ws;
    unsigned short* qb   = (unsigned short*)ws;                       // 2 MB
    unsigned short* kmat = qb + rows * H_DIM;                         // 2 MB
    unsigned short* vP   = kmat + rows * H_DIM;                       // 2 MB
    unsigned short* wt   = vP + rows * H_DIM;                         // 384 KB

    wprep<<<48, 256, 0, stream>>>(Wq, Wk, Wv, wt);
    qkv_gemm<<<256, 512, 0, stream>>>(x, wt, bq, bk, bv, qb, kmat, vP);
    attn_mfma<<<512, 512, 0, stream>>>(qb, kmat, vP, out);
}

// Round 8
// 63.016 us; speedup vs baseline: 1.3881x; 1.3881x over previous
//
#include <hip/hip_runtime.h>
#include <hip/hip_bf16.h>

#define T_DIM 4096
#define C_DIM 1024
#define H_DIM 64
#define B_DIM 4

typedef __attribute__((ext_vector_type(8))) short short8v;
typedef __attribute__((ext_vector_type(4))) short short4v;
typedef __attribute__((ext_vector_type(4))) float float4v;

__device__ __forceinline__ unsigned short f2bf(float f) {
    __hip_bfloat16 h = __float2bfloat16(f);
    return *reinterpret_cast<unsigned short*>(&h);
}

// permuted position within a 32-row block for V storage (PV frag = one 16B load)
__device__ __forceinline__ int vperm(int t5) {
    return ((t5 & 12) << 1) | (t5 & 3) | ((t5 & 16) >> 2);
}

#define GLL16(gsrc, ldst)                                                         \
    __builtin_amdgcn_global_load_lds(                                             \
        (const __attribute__((address_space(1))) unsigned int*)(gsrc),            \
        (__attribute__((address_space(3))) unsigned int*)(ldst), 16, 0, 0)

// ---------------------------------------------------------------------------
// W prep via LDS transpose (r6 row-coverage fix retained).
// ---------------------------------------------------------------------------
__global__ __launch_bounds__(256) void wprep(
    const float* __restrict__ Wq, const float* __restrict__ Wk,
    const float* __restrict__ Wv, unsigned short* __restrict__ wt)
{
    __shared__ float tile[64][65];
    const int t  = threadIdx.x;
    const int m  = blockIdx.x >> 4;
    const int k0 = (blockIdx.x & 15) * 64;
    const float* __restrict__ W = (m == 0) ? Wq : (m == 1) ? Wk : Wv;

    const int kr = t >> 4, c4 = (t & 15) * 4;
#pragma unroll
    for (int j = 0; j < 4; ++j) {
        const int row = kr + j * 16;
        const float4 v = *(const float4*)(W + (size_t)(k0 + row) * 64 + c4);
        tile[row][c4 + 0] = v.x; tile[row][c4 + 1] = v.y;
        tile[row][c4 + 2] = v.z; tile[row][c4 + 3] = v.w;
    }
    __syncthreads();

    const int col = t >> 2, q = t & 3;
    short8v s0, s1;
#pragma unroll
    for (int j = 0; j < 8; ++j) s0[j] = (short)f2bf(tile[q * 16 + j][col]);
#pragma unroll
    for (int j = 0; j < 8; ++j) s1[j] = (short)f2bf(tile[q * 16 + 8 + j][col]);
    unsigned short* dst = wt + (size_t)(m * 64 + col) * 1024 + k0 + q * 16;
    *(short8v*)dst = s0;
    *(short8v*)(dst + 8) = s1;
}

// ---------------------------------------------------------------------------
// QKV projection: LDS GEMM, 16x16x32 MFMA. BM=32 -> grid 512 -> 2 blocks/CU
// (LDS 57KB) so one block computes while the other drains its barrier.
// 512 thr = 8 waves = 2 rg(16r) x 2 cgr(96c) x 2 kh (K-half of each BK=64
// step; combined at end via LDS). Per wave-step: 1 A + 6 B ds_read_b128 +
// 6 MFMA. x reg-staged bf16 (issue-early/write-late), wt via global_load_lds
// with inverse-swizzled source; granule-XOR (^row&7) on all LDS tiles.
// ---------------------------------------------------------------------------
__global__ __launch_bounds__(512, 2) void qkv_gemm(
    const float* __restrict__ x, const unsigned short* __restrict__ wt,
    const float* __restrict__ bq, const float* __restrict__ bk,
    const float* __restrict__ bv,
    unsigned short* __restrict__ qb, unsigned short* __restrict__ kmat,
    unsigned short* __restrict__ vP)
{
    __shared__ __align__(16) unsigned char lx[2][4096];    // 32 rows x 128B bf16
    __shared__ __align__(16) unsigned char lw[2][24576];   // 192 cols x 128B bf16

    const int t    = threadIdx.x;
    const int lane = t & 63;
    const int w    = t >> 6;
    const int l15  = lane & 15;
    const int g4   = lane >> 4;          // 0..3
    const int r0   = blockIdx.x * 32;

    const int rg  = w & 1;
    const int cgr = (w >> 1) & 1;
    const int kh  = w >> 2;

    // x staging (threads 0..255): thread -> (row, 16B granule)
    const int srow  = t >> 3;            // 0..31 for t<256
    const int soct  = t & 7;
    const int sphys = soct ^ (srow & 7);
    const float* __restrict__ xsrc = x + (size_t)(r0 + srow) * C_DIM + soct * 8;
    // wt staging: inverse-swizzled source granule
    const int wgs = (t & 7) ^ ((t >> 3) & 7);
    const unsigned char* __restrict__ wB = (const unsigned char*)wt;

    float4v acc[6];
#pragma unroll
    for (int cg = 0; cg < 6; ++cg) acc[cg] = (float4v){0.f, 0.f, 0.f, 0.f};

#define WSTAGE(p, kb)                                                             \
    {                                                                             \
        _Pragma("unroll")                                                         \
        for (int i = 0; i < 3; ++i)                                               \
            GLL16(wB + (size_t)(i * 64 + (t >> 3)) * 2048 + (kb) * 128 + wgs * 16,\
                  &lw[p][(i * 512 + t) * 16]);                                    \
    }

    // prologue: stage step 0
    WSTAGE(0, 0);
    if (t < 256) {
        const float4 a0 = *(const float4*)(xsrc);
        const float4 a1 = *(const float4*)(xsrc + 4);
        short8v xs;
        xs[0] = (short)f2bf(a0.x); xs[1] = (short)f2bf(a0.y);
        xs[2] = (short)f2bf(a0.z); xs[3] = (short)f2bf(a0.w);
        xs[4] = (short)f2bf(a1.x); xs[5] = (short)f2bf(a1.y);
        xs[6] = (short)f2bf(a1.z); xs[7] = (short)f2bf(a1.w);
        *(short8v*)&lx[0][srow * 128 + sphys * 16] = xs;
    }
    __syncthreads();

    const int arow = rg * 16 + l15;
    const int axor = arow & 7;
    const int kg   = kh * 4 + g4;        // this wave-lane's k granule (0..7)

    for (int kb = 0; kb < 16; ++kb) {
        const int p = kb & 1;
        float4 na = {0,0,0,0}, nb = {0,0,0,0};
        if (kb < 15) {
            if (t < 256) {
                na = *(const float4*)(xsrc + (kb + 1) * 64);
                nb = *(const float4*)(xsrc + (kb + 1) * 64 + 4);
            }
            WSTAGE(p ^ 1, kb + 1);
        }

        const short8v af = *(const short8v*)&lx[p][arow * 128 + (kg ^ axor) * 16];
#pragma unroll
        for (int cg = 0; cg < 6; ++cg) {
            const int col = cgr * 96 + cg * 16 + l15;
            const short8v bf =
                *(const short8v*)&lw[p][col * 128 + ((kg ^ (col & 7))) * 16];
            acc[cg] = __builtin_amdgcn_mfma_f32_16x16x32_bf16(af, bf, acc[cg], 0, 0, 0);
        }

        if (kb < 15 && t < 256) {
            short8v xs;
            xs[0] = (short)f2bf(na.x); xs[1] = (short)f2bf(na.y);
            xs[2] = (short)f2bf(na.z); xs[3] = (short)f2bf(na.w);
            xs[4] = (short)f2bf(nb.x); xs[5] = (short)f2bf(nb.y);
            xs[6] = (short)f2bf(nb.z); xs[7] = (short)f2bf(nb.w);
            *(short8v*)&lx[p ^ 1][srow * 128 + sphys * 16] = xs;
        }
        __syncthreads();
    }

    // K-half combine through LDS (reuse lw after final barrier)
    float* comm = (float*)lw;
    if (kh == 1) {
        const int base = ((w - 4) * 64 + lane) * 24;
#pragma unroll
        for (int cg = 0; cg < 6; ++cg)
#pragma unroll
            for (int e = 0; e < 4; ++e) comm[base + cg * 4 + e] = acc[cg][e];
    }
    __syncthreads();
    if (kh == 0) {
        const int base = (w * 64 + lane) * 24;
#pragma unroll
        for (int cg = 0; cg < 6; ++cg)
#pragma unroll
            for (int e = 0; e < 4; ++e) acc[cg][e] += comm[base + cg * 4 + e];

        const float qs = 0.03125f * 1.44269504088896f;  // C^-0.5 * log2(e)
#pragma unroll
        for (int cg = 0; cg < 6; ++cg) {
            const int cabs = cgr * 96 + cg * 16 + l15;
            const int m    = cabs >> 6;
            const int h    = cabs & 63;
            const float bb = ((m == 0) ? bq : (m == 1) ? bk : bv)[h];
#pragma unroll
            for (int rr = 0; rr < 4; ++rr) {
                const int row = r0 + rg * 16 + 4 * g4 + rr;
                const float vv = acc[cg][rr] + bb;
                if (m == 0) {
                    qb[(size_t)row * 64 + h] = f2bf(vv * qs);
                } else if (m == 1) {
                    kmat[(size_t)row * 64 + h] = f2bf(vv);
                } else {
                    const int b_i = row >> 12;
                    const int tt  = row & 4095;
                    const int tp  = (tt & ~31) | vperm(tt & 31);
                    vP[((size_t)b_i * 64 + h) * T_DIM + tp] = f2bf(vv);
                }
            }
        }
    }
#undef WSTAGE
}

// ---------------------------------------------------------------------------
// Causal attention (round-4 structure, measured ~27us; r7 manual prefetch
// reverted — it spilled). Mods vs r4: f32 lsum (no bf2f round-trips) and a
// wave-uniform unmasked fast path for fully-below-diagonal steps.
// grid 512 x 512 thr (8 waves); block = 32 q-rows x batch; waves split kv
// 8 ways; each wave does two 16-row q tiles. 8-way LDS combine.
// ---------------------------------------------------------------------------
__global__ __launch_bounds__(512, 4) void attn_mfma(
    const unsigned short* __restrict__ qb, const unsigned short* __restrict__ kmat,
    const unsigned short* __restrict__ vP, float* __restrict__ out)
{
    __shared__ float partO[8][32][68];
    __shared__ float partl[8][32];

    const int w    = threadIdx.x >> 6;
    const int lane = threadIdx.x & 63;
    const int l15  = lane & 15;
    const int g    = lane >> 4;
    const int i    = blockIdx.x;
    const int p2   = (i & 255) >> 2;
    const int b    = i & 3;
    const int tt   = (i < 256) ? (127 - p2) : p2;
    const int q0   = tt * 32;
    const int n    = tt + 1;

    const unsigned short* __restrict__ qbase = qb + ((size_t)b * T_DIM + q0) * 64;
    short8v qf[2][2];
    qf[0][0] = *(const short8v*)(qbase + (size_t)l15 * 64 + 8 * g);
    qf[0][1] = *(const short8v*)(qbase + (size_t)l15 * 64 + 32 + 8 * g);
    qf[1][0] = *(const short8v*)(qbase + (size_t)(16 + l15) * 64 + 8 * g);
    qf[1][1] = *(const short8v*)(qbase + (size_t)(16 + l15) * 64 + 32 + 8 * g);

    const unsigned short* __restrict__ kbase = kmat + (size_t)b * T_DIM * 64;
    const unsigned short* __restrict__ vbase = vP + (size_t)b * 64 * T_DIM;

    float4v acc[2][4];
#pragma unroll
    for (int qt = 0; qt < 2; ++qt)
#pragma unroll
        for (int f = 0; f < 4; ++f) acc[qt][f] = (float4v){0.f, 0.f, 0.f, 0.f};
    float lsum[2] = {0.f, 0.f};

    const int rem = n & 7;
    const int cnt = (n >> 3) + (w < rem ? 1 : 0);
    const int st  = w * (n >> 3) + (w < rem ? w : rem);

    for (int s = 0; s < cnt; ++s) {
        const int kv0 = (st + s) * 32;

        const unsigned short* kr0 = kbase + (size_t)(kv0 + l15) * 64 + 8 * g;
        const unsigned short* kr1 = kr0 + 16 * 64;
        const short8v ka0 = *(const short8v*)kr0;
        const short8v ka1 = *(const short8v*)(kr0 + 32);
        const short8v ka2 = *(const short8v*)kr1;
        const short8v ka3 = *(const short8v*)(kr1 + 32);

        short8v vb4[4];
#pragma unroll
        for (int f = 0; f < 4; ++f)
            vb4[f] = *(const short8v*)(
                vbase + (size_t)(f * 16 + l15) * T_DIM + kv0 + 8 * g);

#pragma unroll
        for (int qt = 0; qt < 2; ++qt) {
            const float4v z = (float4v){0.f, 0.f, 0.f, 0.f};
            float4v slo = __builtin_amdgcn_mfma_f32_16x16x32_bf16(ka0, qf[qt][0], z, 0, 0, 0);
            slo = __builtin_amdgcn_mfma_f32_16x16x32_bf16(ka1, qf[qt][1], slo, 0, 0, 0);
            float4v shi = __builtin_amdgcn_mfma_f32_16x16x32_bf16(ka2, qf[qt][0], z, 0, 0, 0);
            shi = __builtin_amdgcn_mfma_f32_16x16x32_bf16(ka3, qf[qt][1], shi, 0, 0, 0);

            short8v pa;
            float ls = 0.f;
            if (kv0 + 31 <= q0 + 16 * qt) {         // fully below diagonal (all lanes)
#pragma unroll
                for (int r = 0; r < 4; ++r) {
                    const float plo = exp2f(slo[r]);
                    const float phi = exp2f(shi[r]);
                    pa[r]     = (short)f2bf(plo);
                    pa[4 + r] = (short)f2bf(phi);
                    ls += plo + phi;
                }
            } else {
                const int qabs = q0 + 16 * qt + l15;
#pragma unroll
                for (int r = 0; r < 4; ++r) {
                    const int kvlo = kv0 + 4 * g + r;
                    const float plo = (kvlo <= qabs) ? exp2f(slo[r]) : 0.f;
                    const float phi = (kvlo + 16 <= qabs) ? exp2f(shi[r]) : 0.f;
                    pa[r]     = (short)f2bf(plo);
                    pa[4 + r] = (short)f2bf(phi);
                    ls += plo + phi;
                }
            }
            lsum[qt] += ls;
#pragma unroll
            for (int f = 0; f < 4; ++f)
                acc[qt][f] = __builtin_amdgcn_mfma_f32_16x16x32_bf16(pa, vb4[f], acc[qt][f], 0, 0, 0);
        }
    }

    // per-wave l reduction across g groups (lanes with same l15 share q row)
#pragma unroll
    for (int qt = 0; qt < 2; ++qt) {
        lsum[qt] += __shfl_xor(lsum[qt], 16);
        lsum[qt] += __shfl_xor(lsum[qt], 32);
    }

#pragma unroll
    for (int qt = 0; qt < 2; ++qt)
#pragma unroll
        for (int f = 0; f < 4; ++f)
#pragma unroll
            for (int r = 0; r < 4; ++r)
                partO[w][16 * qt + 4 * g + r][16 * f + l15] = acc[qt][f][r];
    if (g == 0) {
        partl[w][l15]      = lsum[0];
        partl[w][16 + l15] = lsum[1];
    }
    __syncthreads();

    const int row = threadIdx.x >> 4;
    const int c0  = (threadIdx.x & 15) * 4;
    float lt = 0.f;
#pragma unroll
    for (int ww = 0; ww < 8; ++ww) lt += partl[ww][row];
    const float inv = 1.f / lt;
    float4 o = make_float4(0.f, 0.f, 0.f, 0.f);
#pragma unroll
    for (int ww = 0; ww < 8; ++ww) {
        const float4 s = *(const float4*)&partO[ww][row][c0];
        o.x += s.x; o.y += s.y; o.z += s.z; o.w += s.w;
    }
    o.x *= inv; o.y *= inv; o.z *= inv; o.w *= inv;
    *(float4*)(out + ((size_t)b * T_DIM + q0 + row) * 64 + c0) = o;
}

extern "C" void kernel_launch(void* const* d_in, const int* in_sizes, int n_in,
                              void* d_out, int out_size, void* d_ws, size_t ws_size,
                              hipStream_t stream) {
    const float* x  = (const float*)d_in[0];
    const float* Wq = (const float*)d_in[1];
    const float* bq = (const float*)d_in[2];
    const float* Wk = (const float*)d_in[3];
    const float* bk = (const float*)d_in[4];
    const float* Wv = (const float*)d_in[5];
    const float* bv = (const float*)d_in[6];
    float* out = (float*)d_out;

    const size_t rows = (size_t)B_DIM * T_DIM;            // 16384
    char* ws = (char*)d_ws;
    unsigned short* qb   = (unsigned short*)ws;                       // 2 MB
    unsigned short* kmat = qb + rows * H_DIM;                         // 2 MB
    unsigned short* vP   = kmat + rows * H_DIM;                       // 2 MB
    unsigned short* wt   = vP + rows * H_DIM;                         // 384 KB

    wprep<<<48, 256, 0, stream>>>(Wq, Wk, Wv, wt);
    qkv_gemm<<<512, 512, 0, stream>>>(x, wt, bq, bk, bv, qb, kmat, vP);
    attn_mfma<<<512, 512, 0, stream>>>(qb, kmat, vP, out);
}

// Round 9
// 61.998 us; speedup vs baseline: 1.4109x; 1.0164x over previous
//
#include <hip/hip_runtime.h>
#include <hip/hip_bf16.h>

#define T_DIM 4096
#define C_DIM 1024
#define H_DIM 64
#define B_DIM 4

typedef __attribute__((ext_vector_type(8))) short short8v;
typedef __attribute__((ext_vector_type(4))) short short4v;
typedef __attribute__((ext_vector_type(4))) float float4v;

__device__ __forceinline__ unsigned short f2bf(float f) {
    __hip_bfloat16 h = __float2bfloat16(f);
    return *reinterpret_cast<unsigned short*>(&h);
}

// permuted position within a 32-row block for V storage (PV frag = one 16B load)
__device__ __forceinline__ int vperm(int t5) {
    return ((t5 & 12) << 1) | (t5 & 3) | ((t5 & 16) >> 2);
}

#define GLL16(gsrc, ldst)                                                         \
    __builtin_amdgcn_global_load_lds(                                             \
        (const __attribute__((address_space(1))) unsigned int*)(gsrc),            \
        (__attribute__((address_space(3))) unsigned int*)(ldst), 16, 0, 0)

// ---------------------------------------------------------------------------
// W prep via LDS transpose (unchanged from r8).
// ---------------------------------------------------------------------------
__global__ __launch_bounds__(256) void wprep(
    const float* __restrict__ Wq, const float* __restrict__ Wk,
    const float* __restrict__ Wv, unsigned short* __restrict__ wt)
{
    __shared__ float tile[64][65];
    const int t  = threadIdx.x;
    const int m  = blockIdx.x >> 4;
    const int k0 = (blockIdx.x & 15) * 64;
    const float* __restrict__ W = (m == 0) ? Wq : (m == 1) ? Wk : Wv;

    const int kr = t >> 4, c4 = (t & 15) * 4;
#pragma unroll
    for (int j = 0; j < 4; ++j) {
        const int row = kr + j * 16;
        const float4 v = *(const float4*)(W + (size_t)(k0 + row) * 64 + c4);
        tile[row][c4 + 0] = v.x; tile[row][c4 + 1] = v.y;
        tile[row][c4 + 2] = v.z; tile[row][c4 + 3] = v.w;
    }
    __syncthreads();

    const int col = t >> 2, q = t & 3;
    short8v s0, s1;
#pragma unroll
    for (int j = 0; j < 8; ++j) s0[j] = (short)f2bf(tile[q * 16 + j][col]);
#pragma unroll
    for (int j = 0; j < 8; ++j) s1[j] = (short)f2bf(tile[q * 16 + 8 + j][col]);
    unsigned short* dst = wt + (size_t)(m * 64 + col) * 1024 + k0 + q * 16;
    *(short8v*)dst = s0;
    *(short8v*)(dst + 8) = s1;
}

// ---------------------------------------------------------------------------
// QKV projection: LDS GEMM, 16x16x32 MFMA, BM=32, grid 512 (2 blocks/CU).
// T4 counted-vmcnt schedule: per step {WSTAGE glls -> sched_barrier ->
// x-load (depth-2 prefetch) -> compute -> cvt+ds_write staged x ->
// s_waitcnt vmcnt(1) lgkmcnt(0) -> raw s_barrier}. The vmcnt(1) drains the
// 3 wt glls but leaves the x HBM load in flight across two barriers.
// x staging: 1 float4/thread (all 512), packed cvt, XOR-swizzled dest.
// ---------------------------------------------------------------------------
__global__ __launch_bounds__(512, 2) void qkv_gemm(
    const float* __restrict__ x, const unsigned short* __restrict__ wt,
    const float* __restrict__ bq, const float* __restrict__ bk,
    const float* __restrict__ bv,
    unsigned short* __restrict__ qb, unsigned short* __restrict__ kmat,
    unsigned short* __restrict__ vP)
{
    __shared__ __align__(16) unsigned char lx[2][4096];    // 32 rows x 128B bf16
    __shared__ __align__(16) unsigned char lw[2][24576];   // 192 cols x 128B bf16

    const int t    = threadIdx.x;
    const int lane = t & 63;
    const int w    = t >> 6;
    const int l15  = lane & 15;
    const int g4   = lane >> 4;
    const int r0   = blockIdx.x * 32;

    const int rg  = w & 1;
    const int cgr = (w >> 1) & 1;
    const int kh  = w >> 2;

    // x staging: thread -> (row, 16B-f32 quad); dest granule XOR-swizzled
    const int srow  = t >> 4;            // 0..31
    const int sq    = t & 15;            // 0..15 (16B f32 chunks)
    const int xbyte = srow * 128 + ((sq >> 1) ^ (srow & 7)) * 16 + (sq & 1) * 8;
    const float* __restrict__ xsrc = x + (size_t)(r0 + srow) * C_DIM + sq * 4;
    // wt staging: inverse-swizzled source granule
    const int wgs = (t & 7) ^ ((t >> 3) & 7);
    const unsigned char* __restrict__ wB = (const unsigned char*)wt;

    float4v acc[6];
#pragma unroll
    for (int cg = 0; cg < 6; ++cg) acc[cg] = (float4v){0.f, 0.f, 0.f, 0.f};

#define WSTAGE(p, kb)                                                             \
    {                                                                             \
        _Pragma("unroll")                                                         \
        for (int i = 0; i < 3; ++i)                                               \
            GLL16(wB + (size_t)(i * 64 + (t >> 3)) * 2048 + (kb) * 128 + wgs * 16,\
                  &lw[p][(i * 512 + t) * 16]);                                    \
    }
#define XCVT_WRITE(p, v)                                                          \
    {                                                                             \
        __hip_bfloat162 c0_ = __float22bfloat162_rn(make_float2((v).x, (v).y));   \
        __hip_bfloat162 c1_ = __float22bfloat162_rn(make_float2((v).z, (v).w));   \
        unsigned int* d_ = (unsigned int*)&lx[p][xbyte];                          \
        d_[0] = *(unsigned int*)&c0_;                                             \
        d_[1] = *(unsigned int*)&c1_;                                             \
    }

    float4 xvA, xvB;

    // prologue: step0 staged directly; step1 x prefetched
    {
        const float4 x0 = *(const float4*)xsrc;
        WSTAGE(0, 0);
        __builtin_amdgcn_sched_barrier(0);   // keep glls before xvA in issue order
        xvA = *(const float4*)(xsrc + 64);
        XCVT_WRITE(0, x0);
        asm volatile("s_waitcnt vmcnt(1) lgkmcnt(0)" ::: "memory");
        __builtin_amdgcn_s_barrier();
        __builtin_amdgcn_sched_barrier(0);
    }

    const int arow = rg * 16 + l15;
    const int axor = arow & 7;
    const int kg   = kh * 4 + g4;

#pragma unroll
    for (int kb = 0; kb < 15; ++kb) {
        const int p = kb & 1;
        WSTAGE(p ^ 1, kb + 1);
        __builtin_amdgcn_sched_barrier(0);   // glls issue before the x load
        const int pf = (kb + 2 < 16) ? (kb + 2) : 15;   // clamp keeps vmcnt uniform
        if ((kb & 1) == 0) xvB = *(const float4*)(xsrc + pf * 64);
        else               xvA = *(const float4*)(xsrc + pf * 64);

        const short8v af = *(const short8v*)&lx[p][arow * 128 + (kg ^ axor) * 16];
#pragma unroll
        for (int cg = 0; cg < 6; ++cg) {
            const int col = cgr * 96 + cg * 16 + l15;
            const short8v bf =
                *(const short8v*)&lw[p][col * 128 + ((kg ^ (col & 7))) * 16];
            acc[cg] = __builtin_amdgcn_mfma_f32_16x16x32_bf16(af, bf, acc[cg], 0, 0, 0);
        }

        if ((kb & 1) == 0) { XCVT_WRITE(p ^ 1, xvA); }
        else               { XCVT_WRITE(p ^ 1, xvB); }

        asm volatile("s_waitcnt vmcnt(1) lgkmcnt(0)" ::: "memory");
        __builtin_amdgcn_s_barrier();
        __builtin_amdgcn_sched_barrier(0);
    }
    // final step kb=15 (buffer 1), no staging
    {
        const short8v af = *(const short8v*)&lx[1][arow * 128 + (kg ^ axor) * 16];
#pragma unroll
        for (int cg = 0; cg < 6; ++cg) {
            const int col = cgr * 96 + cg * 16 + l15;
            const short8v bf =
                *(const short8v*)&lw[1][col * 128 + ((kg ^ (col & 7))) * 16];
            acc[cg] = __builtin_amdgcn_mfma_f32_16x16x32_bf16(af, bf, acc[cg], 0, 0, 0);
        }
    }
    __syncthreads();   // protect lw reuse as comm below

    // K-half combine through LDS
    float* comm = (float*)lw;
    if (kh == 1) {
        const int base = ((w - 4) * 64 + lane) * 24;
#pragma unroll
        for (int cg = 0; cg < 6; ++cg)
#pragma unroll
            for (int e = 0; e < 4; ++e) comm[base + cg * 4 + e] = acc[cg][e];
    }
    __syncthreads();
    if (kh == 0) {
        const int base = (w * 64 + lane) * 24;
#pragma unroll
        for (int cg = 0; cg < 6; ++cg)
#pragma unroll
            for (int e = 0; e < 4; ++e) acc[cg][e] += comm[base + cg * 4 + e];

        const float qs = 0.03125f * 1.44269504088896f;  // C^-0.5 * log2(e)
#pragma unroll
        for (int cg = 0; cg < 6; ++cg) {
            const int cabs = cgr * 96 + cg * 16 + l15;
            const int m    = cabs >> 6;
            const int h    = cabs & 63;
            const float bb = ((m == 0) ? bq : (m == 1) ? bk : bv)[h];
#pragma unroll
            for (int rr = 0; rr < 4; ++rr) {
                const int row = r0 + rg * 16 + 4 * g4 + rr;
                const float vv = acc[cg][rr] + bb;
                if (m == 0) {
                    qb[(size_t)row * 64 + h] = f2bf(vv * qs);
                } else if (m == 1) {
                    kmat[(size_t)row * 64 + h] = f2bf(vv);
                } else {
                    const int b_i = row >> 12;
                    const int tt  = row & 4095;
                    const int tp  = (tt & ~31) | vperm(tt & 31);
                    vP[((size_t)b_i * 64 + h) * T_DIM + tp] = f2bf(vv);
                }
            }
        }
    }
#undef WSTAGE
#undef XCVT_WRITE
}

// ---------------------------------------------------------------------------
// Causal attention (r4 structure) with VALU trims: packed bf16 conversion
// (__float22bfloat162_rn) and l computed by a ones-column MFMA (row sums on
// the matrix pipe; deletes lsum adds + end shuffles, exactly consistent with
// the bf16 P used in PV). grid 512 x 512 thr; block = 32 q-rows x batch;
// 8 waves split kv 8 ways; complementary long/short block pairing.
// ---------------------------------------------------------------------------
__global__ __launch_bounds__(512, 4) void attn_mfma(
    const unsigned short* __restrict__ qb, const unsigned short* __restrict__ kmat,
    const unsigned short* __restrict__ vP, float* __restrict__ out)
{
    __shared__ float partO[8][32][68];
    __shared__ float partl[8][32];

    const int w    = threadIdx.x >> 6;
    const int lane = threadIdx.x & 63;
    const int l15  = lane & 15;
    const int g    = lane >> 4;
    const int i    = blockIdx.x;
    const int p2   = (i & 255) >> 2;
    const int b    = i & 3;
    const int tt   = (i < 256) ? (127 - p2) : p2;
    const int q0   = tt * 32;
    const int n    = tt + 1;

    const unsigned short* __restrict__ qbase = qb + ((size_t)b * T_DIM + q0) * 64;
    short8v qf[2][2];
    qf[0][0] = *(const short8v*)(qbase + (size_t)l15 * 64 + 8 * g);
    qf[0][1] = *(const short8v*)(qbase + (size_t)l15 * 64 + 32 + 8 * g);
    qf[1][0] = *(const short8v*)(qbase + (size_t)(16 + l15) * 64 + 8 * g);
    qf[1][1] = *(const short8v*)(qbase + (size_t)(16 + l15) * 64 + 32 + 8 * g);

    const unsigned short* __restrict__ kbase = kmat + (size_t)b * T_DIM * 64;
    const unsigned short* __restrict__ vbase = vP + (size_t)b * 64 * T_DIM;

    short8v kones;
#pragma unroll
    for (int j = 0; j < 8; ++j) kones[j] = (short)0x3F80;   // bf16(1.0)

    float4v acc[2][4];
    float4v accl[2];
#pragma unroll
    for (int qt = 0; qt < 2; ++qt) {
#pragma unroll
        for (int f = 0; f < 4; ++f) acc[qt][f] = (float4v){0.f, 0.f, 0.f, 0.f};
        accl[qt] = (float4v){0.f, 0.f, 0.f, 0.f};
    }

    const int rem = n & 7;
    const int cnt = (n >> 3) + (w < rem ? 1 : 0);
    const int st  = w * (n >> 3) + (w < rem ? w : rem);

    for (int s = 0; s < cnt; ++s) {
        const int kv0 = (st + s) * 32;

        const unsigned short* kr0 = kbase + (size_t)(kv0 + l15) * 64 + 8 * g;
        const unsigned short* kr1 = kr0 + 16 * 64;
        const short8v ka0 = *(const short8v*)kr0;
        const short8v ka1 = *(const short8v*)(kr0 + 32);
        const short8v ka2 = *(const short8v*)kr1;
        const short8v ka3 = *(const short8v*)(kr1 + 32);

        short8v vb4[4];
#pragma unroll
        for (int f = 0; f < 4; ++f)
            vb4[f] = *(const short8v*)(
                vbase + (size_t)(f * 16 + l15) * T_DIM + kv0 + 8 * g);

#pragma unroll
        for (int qt = 0; qt < 2; ++qt) {
            const float4v z = (float4v){0.f, 0.f, 0.f, 0.f};
            float4v slo = __builtin_amdgcn_mfma_f32_16x16x32_bf16(ka0, qf[qt][0], z, 0, 0, 0);
            slo = __builtin_amdgcn_mfma_f32_16x16x32_bf16(ka1, qf[qt][1], slo, 0, 0, 0);
            float4v shi = __builtin_amdgcn_mfma_f32_16x16x32_bf16(ka2, qf[qt][0], z, 0, 0, 0);
            shi = __builtin_amdgcn_mfma_f32_16x16x32_bf16(ka3, qf[qt][1], shi, 0, 0, 0);

            float pl[4], ph[4];
            if (kv0 + 31 <= q0 + 16 * qt) {         // fully below diagonal
#pragma unroll
                for (int r = 0; r < 4; ++r) {
                    pl[r] = exp2f(slo[r]);
                    ph[r] = exp2f(shi[r]);
                }
            } else {
                const int qabs = q0 + 16 * qt + l15;
#pragma unroll
                for (int r = 0; r < 4; ++r) {
                    const int kvlo = kv0 + 4 * g + r;
                    pl[r] = (kvlo <= qabs) ? exp2f(slo[r]) : 0.f;
                    ph[r] = (kvlo + 16 <= qabs) ? exp2f(shi[r]) : 0.f;
                }
            }
            short8v pa;
            {
                unsigned int* pu = (unsigned int*)&pa;
                __hip_bfloat162 c0 = __float22bfloat162_rn(make_float2(pl[0], pl[1]));
                __hip_bfloat162 c1 = __float22bfloat162_rn(make_float2(pl[2], pl[3]));
                __hip_bfloat162 c2 = __float22bfloat162_rn(make_float2(ph[0], ph[1]));
                __hip_bfloat162 c3 = __float22bfloat162_rn(make_float2(ph[2], ph[3]));
                pu[0] = *(unsigned int*)&c0;
                pu[1] = *(unsigned int*)&c1;
                pu[2] = *(unsigned int*)&c2;
                pu[3] = *(unsigned int*)&c3;
            }
#pragma unroll
            for (int f = 0; f < 4; ++f)
                acc[qt][f] = __builtin_amdgcn_mfma_f32_16x16x32_bf16(pa, vb4[f], acc[qt][f], 0, 0, 0);
            accl[qt] = __builtin_amdgcn_mfma_f32_16x16x32_bf16(pa, kones, accl[qt], 0, 0, 0);
        }
    }

#pragma unroll
    for (int qt = 0; qt < 2; ++qt)
#pragma unroll
        for (int f = 0; f < 4; ++f)
#pragma unroll
            for (int r = 0; r < 4; ++r)
                partO[w][16 * qt + 4 * g + r][16 * f + l15] = acc[qt][f][r];
    if (l15 == 0) {
#pragma unroll
        for (int qt = 0; qt < 2; ++qt)
#pragma unroll
            for (int r = 0; r < 4; ++r)
                partl[w][16 * qt + 4 * g + r] = accl[qt][r];
    }
    __syncthreads();

    const int row = threadIdx.x >> 4;
    const int c0  = (threadIdx.x & 15) * 4;
    float lt = 0.f;
#pragma unroll
    for (int ww = 0; ww < 8; ++ww) lt += partl[ww][row];
    const float inv = 1.f / lt;
    float4 o = make_float4(0.f, 0.f, 0.f, 0.f);
#pragma unroll
    for (int ww = 0; ww < 8; ++ww) {
        const float4 s = *(const float4*)&partO[ww][row][c0];
        o.x += s.x; o.y += s.y; o.z += s.z; o.w += s.w;
    }
    o.x *= inv; o.y *= inv; o.z *= inv; o.w *= inv;
    *(float4*)(out + ((size_t)b * T_DIM + q0 + row) * 64 + c0) = o;
}

extern "C" void kernel_launch(void* const* d_in, const int* in_sizes, int n_in,
                              void* d_out, int out_size, void* d_ws, size_t ws_size,
                              hipStream_t stream) {
    const float* x  = (const float*)d_in[0];
    const float* Wq = (const float*)d_in[1];
    const float* bq = (const float*)d_in[2];
    const float* Wk = (const float*)d_in[3];
    const float* bk = (const float*)d_in[4];
    const float* Wv = (const float*)d_in[5];
    const float* bv = (const float*)d_in[6];
    float* out = (float*)d_out;

    const size_t rows = (size_t)B_DIM * T_DIM;            // 16384
    char* ws = (char*)d_ws;
    unsigned short* qb   = (unsigned short*)ws;                       // 2 MB
    unsigned short* kmat = qb + rows * H_DIM;                         // 2 MB
    unsigned short* vP   = kmat + rows * H_DIM;                       // 2 MB
    unsigned short* wt   = vP + rows * H_DIM;                         // 384 KB

    wprep<<<48, 256, 0, stream>>>(Wq, Wk, Wv, wt);
    qkv_gemm<<<512, 512, 0, stream>>>(x, wt, bq, bk, bv, qb, kmat, vP);
    attn_mfma<<<512, 512, 0, stream>>>(qb, kmat, vP, out);
}